// Round 4
// baseline (39.520 us; speedup 1.0000x reference)
//
#include <hip/hip_runtime.h>
#include <math.h>

#define MAX_COV 10000.0f
#define MIN_COV 0.0001f
#define SYMM_THRESH 1e-05f
#define DET_THRESH 1e-06f
#define MAX_POS 1000.0f
#define EIG_CLAMP 0.0001f
#define INV_EPS 0.0001f

namespace {
constexpr int BS = 256;

__device__ __forceinline__ float rcp_fast(float x)  { return __builtin_amdgcn_rcpf(x); }
__device__ __forceinline__ float sqrt_fast(float x) { return __builtin_amdgcn_sqrtf(x); }

// acos via A&S 4.4.45: |err| <= ~7e-5 rad, branchless.
__device__ __forceinline__ float acos_fast(float x) {
    const float t = fabsf(x);
    const float s = sqrt_fast(fmaxf(1.0f - t, 0.0f));
    float p = fmaf(t, -0.0187293f, 0.0742610f);
    p = fmaf(t, p, -0.2121144f);
    p = fmaf(t, p, 1.5707288f);
    const float a = s * p;
    return (x >= 0.0f) ? a : (3.14159265358979f - a);
}

// Closed-form eigenvalues of a symmetric 3x3 (trig method).
__device__ __forceinline__ void eigvals3(
    float m00, float m01, float m02, float m11, float m12, float m22,
    float& l1, float& l2, float& l3)
{
    const float q   = (m00 + m11 + m22) * (1.0f / 3.0f);
    const float b00 = m00 - q, b11 = m11 - q, b22 = m22 - q;
    const float offsq = m01 * m01 + m02 * m02 + m12 * m12;
    const float p2  = b00 * b00 + b11 * b11 + b22 * b22 + 2.0f * offsq;
    const float p   = sqrt_fast(p2 * (1.0f / 6.0f));
    const float detB =
          b00 * (b11 * b22 - m12 * m12)
        - m01 * (m01 * b22 - m12 * m02)
        + m02 * (m01 * m12 - b11 * m02);
    const float pinv = rcp_fast(fmaxf(p, 1e-30f));
    // left-to-right order: detB==0 with p==0 must give 0, not NaN
    float r = 0.5f * detB;
    r = r * pinv; r = r * pinv; r = r * pinv;
    r = fminf(1.0f, fmaxf(-1.0f, r));
    const float phi = acos_fast(r) * (1.0f / 3.0f);    // [0, pi/3]
    const float c   = __cosf(phi);
    const float s   = sqrt_fast(fmaxf(1.0f - c * c, 0.0f));
    l1 = q + 2.0f * p * c;
    l3 = q + p * (-c - 1.7320508075688772f * s);       // cos(phi+2pi/3) identity
    l2 = 3.0f * q - l1 - l3;
}

__global__ __launch_bounds__(BS, 8)
void wl_kernel(const float* __restrict__ miu1, const float* __restrict__ miu2,
               const float* __restrict__ cov1, const float* __restrict__ cov2,
               float* __restrict__ out, int N)
{
    __shared__ float s_a[BS * 9];
    __shared__ float s_b[BS * 9];

    const int tid  = threadIdx.x;
    const int base = blockIdx.x * BS;
    const int nb   = min(BS, N - base);
    const bool full = (nb == BS);

    float* out_cov = out + (size_t)N * 3;

    // ---- coalesced global -> LDS staging of the two cov tiles ----
    if (full) {
        // base*9 floats = base*36 bytes; base is a multiple of BS=256 -> 16B aligned
        const float4* g1 = (const float4*)(cov1 + (size_t)base * 9);
        const float4* g2 = (const float4*)(cov2 + (size_t)base * 9);
        float4* la = (float4*)s_a;
        float4* lb = (float4*)s_b;
        #pragma unroll
        for (int j = 0; j < 2; ++j) {
            la[tid + j * BS] = g1[tid + j * BS];
            lb[tid + j * BS] = g2[tid + j * BS];
        }
        if (tid < BS * 9 / 4 - 2 * BS) {   // 576 - 512 = 64 remaining float4s
            la[2 * BS + tid] = g1[2 * BS + tid];
            lb[2 * BS + tid] = g2[2 * BS + tid];
        }
    } else {
        for (int j = tid; j < nb * 9; j += BS) {
            s_a[j] = cov1[(size_t)base * 9 + j];
            s_b[j] = cov2[(size_t)base * 9 + j];
        }
    }
    __syncthreads();

    if (tid < nb) {
        const int i = base + tid;
        float c1[9], c2r[9], u1[3], u2[3];
        #pragma unroll
        for (int k = 0; k < 9; ++k) { c1[k] = s_a[tid * 9 + k]; c2r[k] = s_b[tid * 9 + k]; }
        {
            const float* q1p = miu1 + (size_t)i * 3;
            const float* q2p = miu2 + (size_t)i * 3;
            #pragma unroll
            for (int k = 0; k < 3; ++k) { u1[k] = q1p[k]; u2[k] = q2p[k]; }
        }

        // ---- stability mask ----
        float amax1 = 0.0f, amax2 = 0.0f, amin1 = 1e30f, amin2 = 1e30f;
        #pragma unroll
        for (int k = 0; k < 9; ++k) {
            amax1 = fmaxf(amax1, fabsf(c1[k]));  amin1 = fminf(amin1, fabsf(c1[k]));
            amax2 = fmaxf(amax2, fabsf(c2r[k])); amin2 = fminf(amin2, fabsf(c2r[k]));
        }
        bool ok = (amax1 < MAX_COV) && (amax2 < MAX_COV)
               && (amin1 > MIN_COV) && (amin2 > MIN_COV);
        const float sd = fmaxf(fmaxf(fabsf(c1[1] - c1[3]), fabsf(c1[2] - c1[6])),
                        fmaxf(fabsf(c1[5] - c1[7]),
                        fmaxf(fmaxf(fabsf(c2r[1] - c2r[3]), fabsf(c2r[2] - c2r[6])),
                              fabsf(c2r[5] - c2r[7]))));
        ok = ok && (sd < SYMM_THRESH);
        const float det1 = c1[0] * (c1[4] * c1[8] - c1[5] * c1[7])
                         - c1[1] * (c1[3] * c1[8] - c1[5] * c1[6])
                         + c1[2] * (c1[3] * c1[7] - c1[4] * c1[6]);
        const float det2 = c2r[0] * (c2r[4] * c2r[8] - c2r[5] * c2r[7])
                         - c2r[1] * (c2r[3] * c2r[8] - c2r[5] * c2r[6])
                         + c2r[2] * (c2r[3] * c2r[7] - c2r[4] * c2r[6]);
        ok = ok && (fabsf(det1) > DET_THRESH) && (fabsf(det2) > DET_THRESH);
        const float um = fmaxf(fmaxf(fmaxf(fabsf(u1[0]), fabsf(u1[1])), fabsf(u1[2])),
                               fmaxf(fmaxf(fabsf(u2[0]), fabsf(u2[1])), fabsf(u2[2])));
        ok = ok && (um < MAX_POS);

        // ---- symmetrized inputs; masked items -> identity ----
        const float m00 = ok ? c1[0] : 1.0f;
        const float m01 = ok ? (0.5f * (c1[1] + c1[3])) : 0.0f;
        const float m02 = ok ? (0.5f * (c1[2] + c1[6])) : 0.0f;
        const float m11 = ok ? c1[4] : 1.0f;
        const float m12 = ok ? (0.5f * (c1[5] + c1[7])) : 0.0f;
        const float m22 = ok ? c1[8] : 1.0f;
        const float d00 = ok ? c2r[0] : 1.0f;
        const float d01 = ok ? (0.5f * (c2r[1] + c2r[3])) : 0.0f;
        const float d02 = ok ? (0.5f * (c2r[2] + c2r[6])) : 0.0f;
        const float d11 = ok ? c2r[4] : 1.0f;
        const float d12 = ok ? (0.5f * (c2r[5] + c2r[7])) : 0.0f;
        const float d22 = ok ? c2r[8] : 1.0f;

        float l1, l2, l3;
        eigvals3(m00, m01, m02, m11, m12, m22, l1, l2, l3);
        l1 = fmaxf(l1, EIG_CLAMP); l2 = fmaxf(l2, EIG_CLAMP); l3 = fmaxf(l3, EIG_CLAMP);
        const float sa = sqrt_fast(l1), sb = sqrt_fast(l2), sc = sqrt_fast(l3);
        const float i_ab = rcp_fast(sa + sb);
        const float i_bc = rcp_fast(sb + sc);
        const float i_ac = rcp_fast(sa + sc);
        const float q0 = sa, q1 = i_ab, q2 = -i_ab * i_bc * i_ac;
        const float ea = rcp_fast(INV_EPS + sa);
        const float eb = rcp_fast(INV_EPS + sb);
        const float ec = rcp_fast(INV_EPS + sc);
        const float g0 = ea;
        const float g1 = -ea * eb * i_ab;
        const float g2 = (INV_EPS + sa + sb + sc) * ea * eb * ec * i_ab * i_bc * i_ac;

        const float u00 = m00 - l1, u11 = m11 - l1, u22 = m22 - l1;
        const float v00 = m00 - l2, v11 = m11 - l2, v22 = m22 - l2;
        const float P00 = u00 * v00 + m01 * m01 + m02 * m02;
        const float P01 = u00 * m01 + m01 * v11 + m02 * m12;
        const float P02 = u00 * m02 + m01 * m12 + m02 * v22;
        const float P11 = m01 * m01 + u11 * v11 + m12 * m12;
        const float P12 = m01 * m02 + u11 * m12 + m12 * v22;
        const float P22 = m02 * m02 + m12 * m12 + u22 * v22;

        const float S00 = q0 + q1 * u00 + q2 * P00;
        const float S01 =      q1 * m01 + q2 * P01;
        const float S02 =      q1 * m02 + q2 * P02;
        const float S11 = q0 + q1 * u11 + q2 * P11;
        const float S12 =      q1 * m12 + q2 * P12;
        const float S22 = q0 + q1 * u22 + q2 * P22;

        const float G00 = g0 + g1 * u00 + g2 * P00;
        const float G01 =      g1 * m01 + g2 * P01;
        const float G02 =      g1 * m02 + g2 * P02;
        const float G11 = g0 + g1 * u11 + g2 * P11;
        const float G12 =      g1 * m12 + g2 * P12;
        const float G22 = g0 + g1 * u22 + g2 * P22;

        // C = S*D*S (exactly symmetric)
        const float T00 = S00 * d00 + S01 * d01 + S02 * d02;
        const float T01 = S00 * d01 + S01 * d11 + S02 * d12;
        const float T02 = S00 * d02 + S01 * d12 + S02 * d22;
        const float T10 = S01 * d00 + S11 * d01 + S12 * d02;
        const float T11 = S01 * d01 + S11 * d11 + S12 * d12;
        const float T12 = S01 * d02 + S11 * d12 + S12 * d22;
        const float T20 = S02 * d00 + S12 * d01 + S22 * d02;
        const float T21 = S02 * d01 + S12 * d11 + S22 * d12;
        const float T22m = S02 * d02 + S12 * d12 + S22 * d22;
        const float C00 = T00 * S00 + T01 * S01 + T02 * S02;
        const float C01 = T00 * S01 + T01 * S11 + T02 * S12;
        const float C02 = T00 * S02 + T01 * S12 + T02 * S22;
        const float C11 = T10 * S01 + T11 * S11 + T12 * S12;
        const float C12 = T10 * S02 + T11 * S12 + T12 * S22;
        const float C22 = T20 * S02 + T21 * S12 + T22m * S22;

        float e1, e2, e3;
        eigvals3(C00, C01, C02, C11, C12, C22, e1, e2, e3);
        const float ra = sqrt_fast(fabsf(e1));
        const float rb = sqrt_fast(fabsf(e2));
        const float rc = sqrt_fast(fabsf(e3));
        const float j_ab = rcp_fast(fmaxf(ra + rb, 1e-12f));
        const float j_bc = rcp_fast(fmaxf(rb + rc, 1e-12f));
        const float j_ac = rcp_fast(fmaxf(ra + rc, 1e-12f));
        const float h0 = ra, h1 = j_ab, h2 = -j_ab * j_bc * j_ac;
        const float cu00 = C00 - e1, cu11 = C11 - e1, cu22 = C22 - e1;
        const float cv00 = C00 - e2, cv11 = C11 - e2, cv22 = C22 - e2;
        const float R00 = cu00 * cv00 + C01 * C01 + C02 * C02;
        const float R01 = cu00 * C01 + C01 * cv11 + C02 * C12;
        const float R02 = cu00 * C02 + C01 * C12 + C02 * cv22;
        const float R11 = C01 * C01 + cu11 * cv11 + C12 * C12;
        const float R12 = C01 * C02 + cu11 * C12 + C12 * cv22;
        const float R22 = C02 * C02 + C12 * C12 + cu22 * cv22;

        const float X00 = h0 + h1 * cu00 + h2 * R00;
        const float X01 =      h1 * C01  + h2 * R01;
        const float X02 =      h1 * C02  + h2 * R02;
        const float X11 = h0 + h1 * cu11 + h2 * R11;
        const float X12 =      h1 * C12  + h2 * R12;
        const float X22 = h0 + h1 * cu22 + h2 * R22;

        // W = S * X * G
        const float A00 = S00 * X00 + S01 * X01 + S02 * X02;
        const float A01 = S00 * X01 + S01 * X11 + S02 * X12;
        const float A02 = S00 * X02 + S01 * X12 + S02 * X22;
        const float A10 = S01 * X00 + S11 * X01 + S12 * X02;
        const float A11 = S01 * X01 + S11 * X11 + S12 * X12;
        const float A12 = S01 * X02 + S11 * X12 + S12 * X22;
        const float A20 = S02 * X00 + S12 * X01 + S22 * X02;
        const float A21 = S02 * X01 + S12 * X11 + S22 * X12;
        const float A22 = S02 * X02 + S12 * X12 + S22 * X22;
        float W[9];
        W[0] = A00 * G00 + A01 * G01 + A02 * G02;
        W[1] = A00 * G01 + A01 * G11 + A02 * G12;
        W[2] = A00 * G02 + A01 * G12 + A02 * G22;
        W[3] = A10 * G00 + A11 * G01 + A12 * G02;
        W[4] = A10 * G01 + A11 * G11 + A12 * G12;
        W[5] = A10 * G02 + A11 * G12 + A12 * G22;
        W[6] = A20 * G00 + A21 * G01 + A22 * G02;
        W[7] = A20 * G01 + A21 * G11 + A22 * G12;
        W[8] = A20 * G02 + A21 * G12 + A22 * G22;

        // cov_vel = W + W^T - 2*sym(cov_1); write into OWN s_a region (no hazard)
        const float M1f[9] = { m00, m01, m02, m01, m11, m12, m02, m12, m22 };
        #pragma unroll
        for (int r = 0; r < 3; ++r)
            #pragma unroll
            for (int cidx = 0; cidx < 3; ++cidx)
                s_a[tid * 9 + r * 3 + cidx] =
                    ok ? (W[r * 3 + cidx] + W[cidx * 3 + r] - 2.0f * M1f[r * 3 + cidx]) : 0.0f;

        // miu out: direct (small traffic, 3x line inflation acceptable)
        float* om = out + (size_t)i * 3;
        #pragma unroll
        for (int k = 0; k < 3; ++k) om[k] = ok ? (u2[k] - u1[k]) : 0.0f;
    }
    __syncthreads();

    // ---- coalesced LDS -> global store of cov_vel ----
    if (full && ((((size_t)(out_cov + (size_t)base * 9)) & 15) == 0)) {
        float4* go = (float4*)(out_cov + (size_t)base * 9);
        const float4* la = (const float4*)s_a;
        #pragma unroll
        for (int j = 0; j < 2; ++j) go[tid + j * BS] = la[tid + j * BS];
        if (tid < BS * 9 / 4 - 2 * BS) go[2 * BS + tid] = la[2 * BS + tid];
    } else {
        for (int j = tid; j < nb * 9; j += BS) out_cov[(size_t)base * 9 + j] = s_a[j];
    }
}

} // namespace

extern "C" void kernel_launch(void* const* d_in, const int* in_sizes, int n_in,
                              void* d_out, int out_size, void* d_ws, size_t ws_size,
                              hipStream_t stream)
{
    const float* miu1 = (const float*)d_in[0];
    const float* miu2 = (const float*)d_in[1];
    const float* cov1 = (const float*)d_in[2];
    const float* cov2 = (const float*)d_in[3];
    float* out = (float*)d_out;
    const int N = in_sizes[0] / 3;
    const int grid = (N + BS - 1) / BS;
    hipLaunchKernelGGL(wl_kernel, dim3(grid), dim3(BS), 0, stream,
                       miu1, miu2, cov1, cov2, out, N);
}

// Round 5
// 33.822 us; speedup vs baseline: 1.1685x; 1.1685x over previous
//
#include <hip/hip_runtime.h>
#include <math.h>

#define MAX_COV 10000.0f
#define MIN_COV 0.0001f
#define SYMM_THRESH 1e-05f
#define DET_THRESH 1e-06f
#define MAX_POS 1000.0f
#define EIG_CLAMP 0.0001f
#define INV_EPS 0.0001f

namespace {
constexpr int BS = 256;

__device__ __forceinline__ float rcp_fast(float x)  { return __builtin_amdgcn_rcpf(x); }
__device__ __forceinline__ float sqrt_fast(float x) { return __builtin_amdgcn_sqrtf(x); }

// acos via A&S 4.4.45: |err| <= ~7e-5 rad, branchless.
__device__ __forceinline__ float acos_fast(float x) {
    const float t = fabsf(x);
    const float s = sqrt_fast(fmaxf(1.0f - t, 0.0f));
    float p = fmaf(t, -0.0187293f, 0.0742610f);
    p = fmaf(t, p, -0.2121144f);
    p = fmaf(t, p, 1.5707288f);
    const float a = s * p;
    return (x >= 0.0f) ? a : (3.14159265358979f - a);
}

// Closed-form eigenvalues of a symmetric 3x3 (trig method).
__device__ __forceinline__ void eigvals3(
    float m00, float m01, float m02, float m11, float m12, float m22,
    float& l1, float& l2, float& l3)
{
    const float q   = (m00 + m11 + m22) * (1.0f / 3.0f);
    const float b00 = m00 - q, b11 = m11 - q, b22 = m22 - q;
    const float offsq = m01 * m01 + m02 * m02 + m12 * m12;
    const float p2  = b00 * b00 + b11 * b11 + b22 * b22 + 2.0f * offsq;
    const float p   = sqrt_fast(p2 * (1.0f / 6.0f));
    const float detB =
          b00 * (b11 * b22 - m12 * m12)
        - m01 * (m01 * b22 - m12 * m02)
        + m02 * (m01 * m12 - b11 * m02);
    const float pinv = rcp_fast(fmaxf(p, 1e-30f));
    // left-to-right order: detB==0 with p==0 must give 0, not NaN
    float r = 0.5f * detB;
    r = r * pinv; r = r * pinv; r = r * pinv;
    r = fminf(1.0f, fmaxf(-1.0f, r));
    const float phi = acos_fast(r) * (1.0f / 3.0f);    // [0, pi/3]
    const float c   = __cosf(phi);
    const float s   = sqrt_fast(fmaxf(1.0f - c * c, 0.0f));
    l1 = q + 2.0f * p * c;
    l3 = q + p * (-c - 1.7320508075688772f * s);       // cos(phi+2pi/3) identity
    l2 = 3.0f * q - l1 - l3;
}

// Entire per-item pipeline: inputs c1,c2 (row-major 3x3), u1,u2 (3).
// Writes wout[9] (cov_vel) and mv[3] (miu_vel).
__device__ __forceinline__ void process_one(
    const float* c1, const float* c2r, const float* u1, const float* u2,
    float* wout, float* mv)
{
    // ---- stability mask ----
    float amax1 = 0.0f, amax2 = 0.0f, amin1 = 1e30f, amin2 = 1e30f;
    #pragma unroll
    for (int k = 0; k < 9; ++k) {
        amax1 = fmaxf(amax1, fabsf(c1[k]));  amin1 = fminf(amin1, fabsf(c1[k]));
        amax2 = fmaxf(amax2, fabsf(c2r[k])); amin2 = fminf(amin2, fabsf(c2r[k]));
    }
    bool ok = (amax1 < MAX_COV) && (amax2 < MAX_COV)
           && (amin1 > MIN_COV) && (amin2 > MIN_COV);
    const float sd = fmaxf(fmaxf(fabsf(c1[1] - c1[3]), fabsf(c1[2] - c1[6])),
                    fmaxf(fabsf(c1[5] - c1[7]),
                    fmaxf(fmaxf(fabsf(c2r[1] - c2r[3]), fabsf(c2r[2] - c2r[6])),
                          fabsf(c2r[5] - c2r[7]))));
    ok = ok && (sd < SYMM_THRESH);
    const float det1 = c1[0] * (c1[4] * c1[8] - c1[5] * c1[7])
                     - c1[1] * (c1[3] * c1[8] - c1[5] * c1[6])
                     + c1[2] * (c1[3] * c1[7] - c1[4] * c1[6]);
    const float det2 = c2r[0] * (c2r[4] * c2r[8] - c2r[5] * c2r[7])
                     - c2r[1] * (c2r[3] * c2r[8] - c2r[5] * c2r[6])
                     + c2r[2] * (c2r[3] * c2r[7] - c2r[4] * c2r[6]);
    ok = ok && (fabsf(det1) > DET_THRESH) && (fabsf(det2) > DET_THRESH);
    const float um = fmaxf(fmaxf(fmaxf(fabsf(u1[0]), fabsf(u1[1])), fabsf(u1[2])),
                           fmaxf(fmaxf(fabsf(u2[0]), fabsf(u2[1])), fabsf(u2[2])));
    ok = ok && (um < MAX_POS);

    // ---- symmetrized inputs; masked items -> identity ----
    const float m00 = ok ? c1[0] : 1.0f;
    const float m01 = ok ? (0.5f * (c1[1] + c1[3])) : 0.0f;
    const float m02 = ok ? (0.5f * (c1[2] + c1[6])) : 0.0f;
    const float m11 = ok ? c1[4] : 1.0f;
    const float m12 = ok ? (0.5f * (c1[5] + c1[7])) : 0.0f;
    const float m22 = ok ? c1[8] : 1.0f;
    const float d00 = ok ? c2r[0] : 1.0f;
    const float d01 = ok ? (0.5f * (c2r[1] + c2r[3])) : 0.0f;
    const float d02 = ok ? (0.5f * (c2r[2] + c2r[6])) : 0.0f;
    const float d11 = ok ? c2r[4] : 1.0f;
    const float d12 = ok ? (0.5f * (c2r[5] + c2r[7])) : 0.0f;
    const float d22 = ok ? c2r[8] : 1.0f;

    float l1, l2, l3;
    eigvals3(m00, m01, m02, m11, m12, m22, l1, l2, l3);
    l1 = fmaxf(l1, EIG_CLAMP); l2 = fmaxf(l2, EIG_CLAMP); l3 = fmaxf(l3, EIG_CLAMP);
    const float sa = sqrt_fast(l1), sb = sqrt_fast(l2), sc = sqrt_fast(l3);
    const float i_ab = rcp_fast(sa + sb);
    const float i_bc = rcp_fast(sb + sc);
    const float i_ac = rcp_fast(sa + sc);
    const float q0 = sa, q1 = i_ab, q2 = -i_ab * i_bc * i_ac;
    const float ea = rcp_fast(INV_EPS + sa);
    const float eb = rcp_fast(INV_EPS + sb);
    const float ec = rcp_fast(INV_EPS + sc);
    const float g0 = ea;
    const float g1 = -ea * eb * i_ab;
    const float g2 = (INV_EPS + sa + sb + sc) * ea * eb * ec * i_ab * i_bc * i_ac;

    const float u00 = m00 - l1, u11 = m11 - l1, u22 = m22 - l1;
    const float v00 = m00 - l2, v11 = m11 - l2, v22 = m22 - l2;
    const float P00 = u00 * v00 + m01 * m01 + m02 * m02;
    const float P01 = u00 * m01 + m01 * v11 + m02 * m12;
    const float P02 = u00 * m02 + m01 * m12 + m02 * v22;
    const float P11 = m01 * m01 + u11 * v11 + m12 * m12;
    const float P12 = m01 * m02 + u11 * m12 + m12 * v22;
    const float P22 = m02 * m02 + m12 * m12 + u22 * v22;

    const float S00 = q0 + q1 * u00 + q2 * P00;
    const float S01 =      q1 * m01 + q2 * P01;
    const float S02 =      q1 * m02 + q2 * P02;
    const float S11 = q0 + q1 * u11 + q2 * P11;
    const float S12 =      q1 * m12 + q2 * P12;
    const float S22 = q0 + q1 * u22 + q2 * P22;

    const float G00 = g0 + g1 * u00 + g2 * P00;
    const float G01 =      g1 * m01 + g2 * P01;
    const float G02 =      g1 * m02 + g2 * P02;
    const float G11 = g0 + g1 * u11 + g2 * P11;
    const float G12 =      g1 * m12 + g2 * P12;
    const float G22 = g0 + g1 * u22 + g2 * P22;

    // C = S*D*S (exactly symmetric)
    const float T00 = S00 * d00 + S01 * d01 + S02 * d02;
    const float T01 = S00 * d01 + S01 * d11 + S02 * d12;
    const float T02 = S00 * d02 + S01 * d12 + S02 * d22;
    const float T10 = S01 * d00 + S11 * d01 + S12 * d02;
    const float T11 = S01 * d01 + S11 * d11 + S12 * d12;
    const float T12 = S01 * d02 + S11 * d12 + S12 * d22;
    const float T20 = S02 * d00 + S12 * d01 + S22 * d02;
    const float T21 = S02 * d01 + S12 * d11 + S22 * d12;
    const float T22m = S02 * d02 + S12 * d12 + S22 * d22;
    const float C00 = T00 * S00 + T01 * S01 + T02 * S02;
    const float C01 = T00 * S01 + T01 * S11 + T02 * S12;
    const float C02 = T00 * S02 + T01 * S12 + T02 * S22;
    const float C11 = T10 * S01 + T11 * S11 + T12 * S12;
    const float C12 = T10 * S02 + T11 * S12 + T12 * S22;
    const float C22 = T20 * S02 + T21 * S12 + T22m * S22;

    float e1, e2, e3;
    eigvals3(C00, C01, C02, C11, C12, C22, e1, e2, e3);
    const float ra = sqrt_fast(fabsf(e1));
    const float rb = sqrt_fast(fabsf(e2));
    const float rc = sqrt_fast(fabsf(e3));
    const float j_ab = rcp_fast(fmaxf(ra + rb, 1e-12f));
    const float j_bc = rcp_fast(fmaxf(rb + rc, 1e-12f));
    const float j_ac = rcp_fast(fmaxf(ra + rc, 1e-12f));
    const float h0 = ra, h1 = j_ab, h2 = -j_ab * j_bc * j_ac;
    const float cu00 = C00 - e1, cu11 = C11 - e1, cu22 = C22 - e1;
    const float cv00 = C00 - e2, cv11 = C11 - e2, cv22 = C22 - e2;
    const float R00 = cu00 * cv00 + C01 * C01 + C02 * C02;
    const float R01 = cu00 * C01 + C01 * cv11 + C02 * C12;
    const float R02 = cu00 * C02 + C01 * C12 + C02 * cv22;
    const float R11 = C01 * C01 + cu11 * cv11 + C12 * C12;
    const float R12 = C01 * C02 + cu11 * C12 + C12 * cv22;
    const float R22 = C02 * C02 + C12 * C12 + cu22 * cv22;

    const float X00 = h0 + h1 * cu00 + h2 * R00;
    const float X01 =      h1 * C01  + h2 * R01;
    const float X02 =      h1 * C02  + h2 * R02;
    const float X11 = h0 + h1 * cu11 + h2 * R11;
    const float X12 =      h1 * C12  + h2 * R12;
    const float X22 = h0 + h1 * cu22 + h2 * R22;

    // W = S * X * G
    const float A00 = S00 * X00 + S01 * X01 + S02 * X02;
    const float A01 = S00 * X01 + S01 * X11 + S02 * X12;
    const float A02 = S00 * X02 + S01 * X12 + S02 * X22;
    const float A10 = S01 * X00 + S11 * X01 + S12 * X02;
    const float A11 = S01 * X01 + S11 * X11 + S12 * X12;
    const float A12 = S01 * X02 + S11 * X12 + S12 * X22;
    const float A20 = S02 * X00 + S12 * X01 + S22 * X02;
    const float A21 = S02 * X01 + S12 * X11 + S22 * X12;
    const float A22 = S02 * X02 + S12 * X12 + S22 * X22;
    float W[9];
    W[0] = A00 * G00 + A01 * G01 + A02 * G02;
    W[1] = A00 * G01 + A01 * G11 + A02 * G12;
    W[2] = A00 * G02 + A01 * G12 + A02 * G22;
    W[3] = A10 * G00 + A11 * G01 + A12 * G02;
    W[4] = A10 * G01 + A11 * G11 + A12 * G12;
    W[5] = A10 * G02 + A11 * G12 + A12 * G22;
    W[6] = A20 * G00 + A21 * G01 + A22 * G02;
    W[7] = A20 * G01 + A21 * G11 + A22 * G12;
    W[8] = A20 * G02 + A21 * G12 + A22 * G22;

    const float M1f[9] = { m00, m01, m02, m01, m11, m12, m02, m12, m22 };
    #pragma unroll
    for (int r = 0; r < 3; ++r)
        #pragma unroll
        for (int cidx = 0; cidx < 3; ++cidx)
            wout[r * 3 + cidx] =
                ok ? (W[r * 3 + cidx] + W[cidx * 3 + r] - 2.0f * M1f[r * 3 + cidx]) : 0.0f;
    #pragma unroll
    for (int k = 0; k < 3; ++k) mv[k] = ok ? (u2[k] - u1[k]) : 0.0f;
}

__global__ __launch_bounds__(BS, 4)
void wl_kernel(const float* __restrict__ miu1, const float* __restrict__ miu2,
               const float* __restrict__ cov1, const float* __restrict__ cov2,
               float* __restrict__ out, int N)
{
    const int t = blockIdx.x * BS + threadIdx.x;
    const long long i0 = (long long)t * 2;
    if (i0 >= N) return;
    const bool has2 = (i0 + 1 < (long long)N);

    float c1[2][9], c2[2][9], u1[2][3], u2[2][3];

    if (has2) {
        // i0 even -> all byte offsets are multiples of 8: float2 loads are safe.
        const float2* p1 = (const float2*)(cov1 + (size_t)i0 * 9);
        const float2* p2 = (const float2*)(cov2 + (size_t)i0 * 9);
        float f1[18], f2[18];
        #pragma unroll
        for (int k = 0; k < 9; ++k) {
            const float2 a = p1[k]; f1[2 * k] = a.x; f1[2 * k + 1] = a.y;
            const float2 b = p2[k]; f2[2 * k] = b.x; f2[2 * k + 1] = b.y;
        }
        #pragma unroll
        for (int k = 0; k < 9; ++k) {
            c1[0][k] = f1[k]; c1[1][k] = f1[9 + k];
            c2[0][k] = f2[k]; c2[1][k] = f2[9 + k];
        }
        const float2* q1 = (const float2*)(miu1 + (size_t)i0 * 3);
        const float2* q2 = (const float2*)(miu2 + (size_t)i0 * 3);
        float g1[6], g2[6];
        #pragma unroll
        for (int k = 0; k < 3; ++k) {
            const float2 a = q1[k]; g1[2 * k] = a.x; g1[2 * k + 1] = a.y;
            const float2 b = q2[k]; g2[2 * k] = b.x; g2[2 * k + 1] = b.y;
        }
        #pragma unroll
        for (int k = 0; k < 3; ++k) {
            u1[0][k] = g1[k]; u1[1][k] = g1[3 + k];
            u2[0][k] = g2[k]; u2[1][k] = g2[3 + k];
        }
    } else {
        // tail: single item, scalar loads; item 1 gets identity (discarded)
        #pragma unroll
        for (int k = 0; k < 9; ++k) {
            c1[0][k] = cov1[(size_t)i0 * 9 + k];
            c2[0][k] = cov2[(size_t)i0 * 9 + k];
            const float idv = (k == 0 || k == 4 || k == 8) ? 1.0f : 0.0f;
            c1[1][k] = idv; c2[1][k] = idv;
        }
        #pragma unroll
        for (int k = 0; k < 3; ++k) {
            u1[0][k] = miu1[(size_t)i0 * 3 + k];
            u2[0][k] = miu2[(size_t)i0 * 3 + k];
            u1[1][k] = 0.0f; u2[1][k] = 0.0f;
        }
    }

    float wout[2][9], mv[2][3];
    #pragma unroll
    for (int s = 0; s < 2; ++s)
        process_one(c1[s], c2[s], u1[s], u2[s], wout[s], mv[s]);

    float* out_cov = out + (size_t)N * 3;
    if (has2) {
        float fo[18], go[6];
        #pragma unroll
        for (int k = 0; k < 9; ++k) { fo[k] = wout[0][k]; fo[9 + k] = wout[1][k]; }
        #pragma unroll
        for (int k = 0; k < 3; ++k) { go[k] = mv[0][k]; go[3 + k] = mv[1][k]; }
        float2* oc = (float2*)(out_cov + (size_t)i0 * 9);
        #pragma unroll
        for (int k = 0; k < 9; ++k) oc[k] = make_float2(fo[2 * k], fo[2 * k + 1]);
        float2* om = (float2*)(out + (size_t)i0 * 3);
        #pragma unroll
        for (int k = 0; k < 3; ++k) om[k] = make_float2(go[2 * k], go[2 * k + 1]);
    } else {
        #pragma unroll
        for (int k = 0; k < 9; ++k) out_cov[(size_t)i0 * 9 + k] = wout[0][k];
        #pragma unroll
        for (int k = 0; k < 3; ++k) out[(size_t)i0 * 3 + k] = mv[0][k];
    }
}

} // namespace

extern "C" void kernel_launch(void* const* d_in, const int* in_sizes, int n_in,
                              void* d_out, int out_size, void* d_ws, size_t ws_size,
                              hipStream_t stream)
{
    const float* miu1 = (const float*)d_in[0];
    const float* miu2 = (const float*)d_in[1];
    const float* cov1 = (const float*)d_in[2];
    const float* cov2 = (const float*)d_in[3];
    float* out = (float*)d_out;
    const int N = in_sizes[0] / 3;
    const int items_per_block = BS * 2;
    const int grid = (N + items_per_block - 1) / items_per_block;
    hipLaunchKernelGGL(wl_kernel, dim3(grid), dim3(BS), 0, stream,
                       miu1, miu2, cov1, cov2, out, N);
}

// Round 6
// 29.523 us; speedup vs baseline: 1.3386x; 1.1456x over previous
//
#include <hip/hip_runtime.h>
#include <math.h>

#define MAX_COV 10000.0f
#define MIN_COV 0.0001f
#define SYMM_THRESH 1e-05f
#define DET_THRESH 1e-06f
#define MAX_POS 1000.0f
#define EIG_CLAMP 0.0001f
#define INV_EPS 0.0001f

namespace {
constexpr int BS = 256;
constexpr int NW = BS / 64;   // waves per block

__device__ __forceinline__ float rcp_fast(float x)  { return __builtin_amdgcn_rcpf(x); }
__device__ __forceinline__ float sqrt_fast(float x) { return __builtin_amdgcn_sqrtf(x); }

// acos via A&S 4.4.45: |err| <= ~7e-5 rad, branchless.
__device__ __forceinline__ float acos_fast(float x) {
    const float t = fabsf(x);
    const float s = sqrt_fast(fmaxf(1.0f - t, 0.0f));
    float p = fmaf(t, -0.0187293f, 0.0742610f);
    p = fmaf(t, p, -0.2121144f);
    p = fmaf(t, p, 1.5707288f);
    const float a = s * p;
    return (x >= 0.0f) ? a : (3.14159265358979f - a);
}

// Closed-form eigenvalues of a symmetric 3x3 (trig method).
__device__ __forceinline__ void eigvals3(
    float m00, float m01, float m02, float m11, float m12, float m22,
    float& l1, float& l2, float& l3)
{
    const float q   = (m00 + m11 + m22) * (1.0f / 3.0f);
    const float b00 = m00 - q, b11 = m11 - q, b22 = m22 - q;
    const float offsq = m01 * m01 + m02 * m02 + m12 * m12;
    const float p2  = b00 * b00 + b11 * b11 + b22 * b22 + 2.0f * offsq;
    const float p   = sqrt_fast(p2 * (1.0f / 6.0f));
    const float detB =
          b00 * (b11 * b22 - m12 * m12)
        - m01 * (m01 * b22 - m12 * m02)
        + m02 * (m01 * m12 - b11 * m02);
    const float pinv = rcp_fast(fmaxf(p, 1e-30f));
    // left-to-right order: detB==0 with p==0 must give 0, not NaN
    float r = 0.5f * detB;
    r = r * pinv; r = r * pinv; r = r * pinv;
    r = fminf(1.0f, fmaxf(-1.0f, r));
    const float phi = acos_fast(r) * (1.0f / 3.0f);    // [0, pi/3]
    const float c   = __cosf(phi);
    const float s   = sqrt_fast(fmaxf(1.0f - c * c, 0.0f));
    l1 = q + 2.0f * p * c;
    l3 = q + p * (-c - 1.7320508075688772f * s);       // cos(phi+2pi/3) identity
    l2 = 3.0f * q - l1 - l3;
}

// Entire per-item pipeline: inputs c1,c2 (row-major 3x3), u1,u2 (3).
// Writes wout[9] (cov_vel) and mv[3] (miu_vel).
__device__ __forceinline__ void process_one(
    const float* c1, const float* c2r, const float* u1, const float* u2,
    float* wout, float* mv)
{
    // ---- stability mask ----
    float amax1 = 0.0f, amax2 = 0.0f, amin1 = 1e30f, amin2 = 1e30f;
    #pragma unroll
    for (int k = 0; k < 9; ++k) {
        amax1 = fmaxf(amax1, fabsf(c1[k]));  amin1 = fminf(amin1, fabsf(c1[k]));
        amax2 = fmaxf(amax2, fabsf(c2r[k])); amin2 = fminf(amin2, fabsf(c2r[k]));
    }
    bool ok = (amax1 < MAX_COV) && (amax2 < MAX_COV)
           && (amin1 > MIN_COV) && (amin2 > MIN_COV);
    const float sd = fmaxf(fmaxf(fabsf(c1[1] - c1[3]), fabsf(c1[2] - c1[6])),
                    fmaxf(fabsf(c1[5] - c1[7]),
                    fmaxf(fmaxf(fabsf(c2r[1] - c2r[3]), fabsf(c2r[2] - c2r[6])),
                          fabsf(c2r[5] - c2r[7]))));
    ok = ok && (sd < SYMM_THRESH);
    const float det1 = c1[0] * (c1[4] * c1[8] - c1[5] * c1[7])
                     - c1[1] * (c1[3] * c1[8] - c1[5] * c1[6])
                     + c1[2] * (c1[3] * c1[7] - c1[4] * c1[6]);
    const float det2 = c2r[0] * (c2r[4] * c2r[8] - c2r[5] * c2r[7])
                     - c2r[1] * (c2r[3] * c2r[8] - c2r[5] * c2r[6])
                     + c2r[2] * (c2r[3] * c2r[7] - c2r[4] * c2r[6]);
    ok = ok && (fabsf(det1) > DET_THRESH) && (fabsf(det2) > DET_THRESH);
    const float um = fmaxf(fmaxf(fmaxf(fabsf(u1[0]), fabsf(u1[1])), fabsf(u1[2])),
                           fmaxf(fmaxf(fabsf(u2[0]), fabsf(u2[1])), fabsf(u2[2])));
    ok = ok && (um < MAX_POS);

    // ---- symmetrized inputs; masked items -> identity ----
    const float m00 = ok ? c1[0] : 1.0f;
    const float m01 = ok ? (0.5f * (c1[1] + c1[3])) : 0.0f;
    const float m02 = ok ? (0.5f * (c1[2] + c1[6])) : 0.0f;
    const float m11 = ok ? c1[4] : 1.0f;
    const float m12 = ok ? (0.5f * (c1[5] + c1[7])) : 0.0f;
    const float m22 = ok ? c1[8] : 1.0f;
    const float d00 = ok ? c2r[0] : 1.0f;
    const float d01 = ok ? (0.5f * (c2r[1] + c2r[3])) : 0.0f;
    const float d02 = ok ? (0.5f * (c2r[2] + c2r[6])) : 0.0f;
    const float d11 = ok ? c2r[4] : 1.0f;
    const float d12 = ok ? (0.5f * (c2r[5] + c2r[7])) : 0.0f;
    const float d22 = ok ? c2r[8] : 1.0f;

    float l1, l2, l3;
    eigvals3(m00, m01, m02, m11, m12, m22, l1, l2, l3);
    l1 = fmaxf(l1, EIG_CLAMP); l2 = fmaxf(l2, EIG_CLAMP); l3 = fmaxf(l3, EIG_CLAMP);
    const float sa = sqrt_fast(l1), sb = sqrt_fast(l2), sc = sqrt_fast(l3);
    const float i_ab = rcp_fast(sa + sb);
    const float i_bc = rcp_fast(sb + sc);
    const float i_ac = rcp_fast(sa + sc);
    const float q0 = sa, q1 = i_ab, q2 = -i_ab * i_bc * i_ac;
    const float ea = rcp_fast(INV_EPS + sa);
    const float eb = rcp_fast(INV_EPS + sb);
    const float ec = rcp_fast(INV_EPS + sc);
    const float g0 = ea;
    const float g1 = -ea * eb * i_ab;
    const float g2 = (INV_EPS + sa + sb + sc) * ea * eb * ec * i_ab * i_bc * i_ac;

    const float u00 = m00 - l1, u11 = m11 - l1, u22 = m22 - l1;
    const float v00 = m00 - l2, v11 = m11 - l2, v22 = m22 - l2;
    const float P00 = u00 * v00 + m01 * m01 + m02 * m02;
    const float P01 = u00 * m01 + m01 * v11 + m02 * m12;
    const float P02 = u00 * m02 + m01 * m12 + m02 * v22;
    const float P11 = m01 * m01 + u11 * v11 + m12 * m12;
    const float P12 = m01 * m02 + u11 * m12 + m12 * v22;
    const float P22 = m02 * m02 + m12 * m12 + u22 * v22;

    const float S00 = q0 + q1 * u00 + q2 * P00;
    const float S01 =      q1 * m01 + q2 * P01;
    const float S02 =      q1 * m02 + q2 * P02;
    const float S11 = q0 + q1 * u11 + q2 * P11;
    const float S12 =      q1 * m12 + q2 * P12;
    const float S22 = q0 + q1 * u22 + q2 * P22;

    const float G00 = g0 + g1 * u00 + g2 * P00;
    const float G01 =      g1 * m01 + g2 * P01;
    const float G02 =      g1 * m02 + g2 * P02;
    const float G11 = g0 + g1 * u11 + g2 * P11;
    const float G12 =      g1 * m12 + g2 * P12;
    const float G22 = g0 + g1 * u22 + g2 * P22;

    // C = S*D*S (exactly symmetric)
    const float T00 = S00 * d00 + S01 * d01 + S02 * d02;
    const float T01 = S00 * d01 + S01 * d11 + S02 * d12;
    const float T02 = S00 * d02 + S01 * d12 + S02 * d22;
    const float T10 = S01 * d00 + S11 * d01 + S12 * d02;
    const float T11 = S01 * d01 + S11 * d11 + S12 * d12;
    const float T12 = S01 * d02 + S11 * d12 + S12 * d22;
    const float T20 = S02 * d00 + S12 * d01 + S22 * d02;
    const float T21 = S02 * d01 + S12 * d11 + S22 * d12;
    const float T22m = S02 * d02 + S12 * d12 + S22 * d22;
    const float C00 = T00 * S00 + T01 * S01 + T02 * S02;
    const float C01 = T00 * S01 + T01 * S11 + T02 * S12;
    const float C02 = T00 * S02 + T01 * S12 + T02 * S22;
    const float C11 = T10 * S01 + T11 * S11 + T12 * S12;
    const float C12 = T10 * S02 + T11 * S12 + T12 * S22;
    const float C22 = T20 * S02 + T21 * S12 + T22m * S22;

    float e1, e2, e3;
    eigvals3(C00, C01, C02, C11, C12, C22, e1, e2, e3);
    const float ra = sqrt_fast(fabsf(e1));
    const float rb = sqrt_fast(fabsf(e2));
    const float rc = sqrt_fast(fabsf(e3));
    const float j_ab = rcp_fast(fmaxf(ra + rb, 1e-12f));
    const float j_bc = rcp_fast(fmaxf(rb + rc, 1e-12f));
    const float j_ac = rcp_fast(fmaxf(ra + rc, 1e-12f));
    const float h0 = ra, h1 = j_ab, h2 = -j_ab * j_bc * j_ac;
    const float cu00 = C00 - e1, cu11 = C11 - e1, cu22 = C22 - e1;
    const float cv00 = C00 - e2, cv11 = C11 - e2, cv22 = C22 - e2;
    const float R00 = cu00 * cv00 + C01 * C01 + C02 * C02;
    const float R01 = cu00 * C01 + C01 * cv11 + C02 * C12;
    const float R02 = cu00 * C02 + C01 * C12 + C02 * cv22;
    const float R11 = C01 * C01 + cu11 * cv11 + C12 * C12;
    const float R12 = C01 * C02 + cu11 * C12 + C12 * cv22;
    const float R22 = C02 * C02 + C12 * C12 + cu22 * cv22;

    const float X00 = h0 + h1 * cu00 + h2 * R00;
    const float X01 =      h1 * C01  + h2 * R01;
    const float X02 =      h1 * C02  + h2 * R02;
    const float X11 = h0 + h1 * cu11 + h2 * R11;
    const float X12 =      h1 * C12  + h2 * R12;
    const float X22 = h0 + h1 * cu22 + h2 * R22;

    // W = S * X * G
    const float A00 = S00 * X00 + S01 * X01 + S02 * X02;
    const float A01 = S00 * X01 + S01 * X11 + S02 * X12;
    const float A02 = S00 * X02 + S01 * X12 + S02 * X22;
    const float A10 = S01 * X00 + S11 * X01 + S12 * X02;
    const float A11 = S01 * X01 + S11 * X11 + S12 * X12;
    const float A12 = S01 * X02 + S11 * X12 + S12 * X22;
    const float A20 = S02 * X00 + S12 * X01 + S22 * X02;
    const float A21 = S02 * X01 + S12 * X11 + S22 * X12;
    const float A22 = S02 * X02 + S12 * X12 + S22 * X22;
    float W[9];
    W[0] = A00 * G00 + A01 * G01 + A02 * G02;
    W[1] = A00 * G01 + A01 * G11 + A02 * G12;
    W[2] = A00 * G02 + A01 * G12 + A02 * G22;
    W[3] = A10 * G00 + A11 * G01 + A12 * G02;
    W[4] = A10 * G01 + A11 * G11 + A12 * G12;
    W[5] = A10 * G02 + A11 * G12 + A12 * G22;
    W[6] = A20 * G00 + A21 * G01 + A22 * G02;
    W[7] = A20 * G01 + A21 * G11 + A22 * G12;
    W[8] = A20 * G02 + A21 * G12 + A22 * G22;

    const float M1f[9] = { m00, m01, m02, m01, m11, m12, m02, m12, m22 };
    #pragma unroll
    for (int r = 0; r < 3; ++r)
        #pragma unroll
        for (int cidx = 0; cidx < 3; ++cidx)
            wout[r * 3 + cidx] =
                ok ? (W[r * 3 + cidx] + W[cidx * 3 + r] - 2.0f * M1f[r * 3 + cidx]) : 0.0f;
    #pragma unroll
    for (int k = 0; k < 3; ++k) mv[k] = ok ? (u2[k] - u1[k]) : 0.0f;
}

__global__ __launch_bounds__(BS, 4)
void wl_kernel(const float* __restrict__ miu1, const float* __restrict__ miu2,
               const float* __restrict__ cov1, const float* __restrict__ cov2,
               float* __restrict__ out, int N)
{
    // Wave-private LDS slices: redistribution without any block barriers.
    __shared__ float s_c1[NW][576];   // 64 items * 9
    __shared__ float s_c2[NW][576];
    __shared__ float s_mu[NW][384];   // miu1 (192) + miu2 (192)

    const int w = threadIdx.x >> 6;          // wave in block
    const int l = threadIdx.x & 63;          // lane
    const int wbase = blockIdx.x * BS + w * 64;  // first item of this wave
    if (wbase >= N) return;

    float* out_cov = out + (size_t)N * 3;
    float c1[9], c2[9], u1[3], u2[3];
    float wout[9], mv[3];

    if (wbase + 64 <= N) {
        // ---- coalesced global -> LDS (lane-stride 4B: minimal line-requests) ----
        const float* g1 = cov1 + (size_t)wbase * 9;
        const float* g2 = cov2 + (size_t)wbase * 9;
        #pragma unroll
        for (int k = 0; k < 9; ++k) {
            s_c1[w][l + 64 * k] = g1[l + 64 * k];
            s_c2[w][l + 64 * k] = g2[l + 64 * k];
        }
        const float* gm1 = miu1 + (size_t)wbase * 3;
        const float* gm2 = miu2 + (size_t)wbase * 3;
        #pragma unroll
        for (int k = 0; k < 3; ++k) {
            s_mu[w][l + 64 * k]       = gm1[l + 64 * k];
            s_mu[w][192 + l + 64 * k] = gm2[l + 64 * k];
        }
        // same-wave LDS producer->consumer: in-order DS pipe, no s_barrier needed;
        // wave_barrier() fences compiler reordering.
        __builtin_amdgcn_wave_barrier();

        // ---- LDS -> per-item registers (stride 9: 2-way bank alias = free) ----
        #pragma unroll
        for (int k = 0; k < 9; ++k) { c1[k] = s_c1[w][l * 9 + k]; c2[k] = s_c2[w][l * 9 + k]; }
        #pragma unroll
        for (int k = 0; k < 3; ++k) { u1[k] = s_mu[w][l * 3 + k]; u2[k] = s_mu[w][192 + l * 3 + k]; }

        process_one(c1, c2, u1, u2, wout, mv);

        // ---- results -> LDS (own slots; reads above already consumed) ----
        __builtin_amdgcn_wave_barrier();
        #pragma unroll
        for (int k = 0; k < 9; ++k) s_c1[w][l * 9 + k] = wout[k];
        #pragma unroll
        for (int k = 0; k < 3; ++k) s_mu[w][l * 3 + k] = mv[k];
        __builtin_amdgcn_wave_barrier();

        // ---- coalesced LDS -> global ----
        float* oc = out_cov + (size_t)wbase * 9;
        #pragma unroll
        for (int k = 0; k < 9; ++k) oc[l + 64 * k] = s_c1[w][l + 64 * k];
        float* om = out + (size_t)wbase * 3;
        #pragma unroll
        for (int k = 0; k < 3; ++k) om[l + 64 * k] = s_mu[w][l + 64 * k];
    } else {
        // tail wave: plain per-thread path
        const int i = wbase + l;
        if (i >= N) return;
        #pragma unroll
        for (int k = 0; k < 9; ++k) {
            c1[k] = cov1[(size_t)i * 9 + k];
            c2[k] = cov2[(size_t)i * 9 + k];
        }
        #pragma unroll
        for (int k = 0; k < 3; ++k) {
            u1[k] = miu1[(size_t)i * 3 + k];
            u2[k] = miu2[(size_t)i * 3 + k];
        }
        process_one(c1, c2, u1, u2, wout, mv);
        #pragma unroll
        for (int k = 0; k < 9; ++k) out_cov[(size_t)i * 9 + k] = wout[k];
        #pragma unroll
        for (int k = 0; k < 3; ++k) out[(size_t)i * 3 + k] = mv[k];
    }
}

} // namespace

extern "C" void kernel_launch(void* const* d_in, const int* in_sizes, int n_in,
                              void* d_out, int out_size, void* d_ws, size_t ws_size,
                              hipStream_t stream)
{
    const float* miu1 = (const float*)d_in[0];
    const float* miu2 = (const float*)d_in[1];
    const float* cov1 = (const float*)d_in[2];
    const float* cov2 = (const float*)d_in[3];
    float* out = (float*)d_out;
    const int N = in_sizes[0] / 3;
    const int grid = (N + BS - 1) / BS;
    hipLaunchKernelGGL(wl_kernel, dim3(grid), dim3(BS), 0, stream,
                       miu1, miu2, cov1, cov2, out, N);
}

// Round 7
// 28.713 us; speedup vs baseline: 1.3764x; 1.0282x over previous
//
#include <hip/hip_runtime.h>
#include <math.h>

#define MAX_COV 10000.0f
#define MIN_COV 0.0001f
#define SYMM_THRESH 1e-05f
#define DET_THRESH 1e-06f
#define MAX_POS 1000.0f
#define EIG_CLAMP 0.0001f
#define INV_EPS 0.0001f

namespace {
constexpr int BS = 256;

typedef float v2f __attribute__((ext_vector_type(2)));
__device__ __forceinline__ v2f mk2(float a, float b) { v2f r; r[0] = a; r[1] = b; return r; }

__device__ __forceinline__ float rcp_fast(float x)  { return __builtin_amdgcn_rcpf(x); }
__device__ __forceinline__ float sqrt_fast(float x) { return __builtin_amdgcn_sqrtf(x); }

// acos(x)/3 via A&S 4.4.45 with 1/3 folded into the coefficients.
__device__ __forceinline__ float acos3_fast(float x) {
    const float t = fabsf(x);
    const float s = sqrt_fast(fmaxf(1.0f - t, 0.0f));
    float p = fmaf(t, -0.00624310f, 0.02475367f);
    p = fmaf(t, p, -0.07070480f);
    p = fmaf(t, p, 0.52357627f);
    const float a3 = s * p;                       // acos(|x|)/3
    return (x >= 0.0f) ? a3 : (1.0471975512f - a3); // pi/3 - a3
}

// Closed-form eigenvalues of a symmetric 3x3 (trig method).
__device__ __forceinline__ void eigvals3(
    float m00, float m01, float m02, float m11, float m12, float m22,
    float& l1, float& l2, float& l3)
{
    const float q   = (m00 + m11 + m22) * (1.0f / 3.0f);
    const float b00 = m00 - q, b11 = m11 - q, b22 = m22 - q;
    const float offsq = m01 * m01 + m02 * m02 + m12 * m12;
    const float p2  = b00 * b00 + b11 * b11 + b22 * b22 + 2.0f * offsq;
    const float p   = sqrt_fast(p2 * (1.0f / 6.0f));
    const float detB =
          b00 * (b11 * b22 - m12 * m12)
        - m01 * (m01 * b22 - m12 * m02)
        + m02 * (m01 * m12 - b11 * m02);
    const float pinv  = rcp_fast(fmaxf(p, 1e-30f));
    const float pinv3 = pinv * pinv * pinv;       // computed in parallel with detB
    // p==0 (masked identity) -> detB==0 -> 0*inf = NaN; the clamp below drops
    // NaN (v_max/v_min are IEEE maxNum/minNum) -> r=-1 -> eigvals = q. Correct.
    float r = (0.5f * detB) * pinv3;
    r = fminf(1.0f, fmaxf(-1.0f, r));
    const float phi = acos3_fast(r);              // [0, pi/3]
    const float c   = __cosf(phi);                // parallel trans ops
    const float s   = __sinf(phi);                // (phi small: no range issues)
    l1 = q + 2.0f * p * c;
    l3 = q + p * (-c - 1.7320508075688772f * s);  // cos(phi+2pi/3) identity
    l2 = 3.0f * q - l1 - l3;
}

__global__ __launch_bounds__(BS, 4)
void wl_kernel(const float* __restrict__ miu1, const float* __restrict__ miu2,
               const float* __restrict__ cov1, const float* __restrict__ cov2,
               float* __restrict__ out, int N)
{
    const int i = blockIdx.x * BS + threadIdx.x;
    if (i >= N) return;

    float c1[9], c2r[9], u1[3], u2[3];
    {
        const float* p1 = cov1 + (size_t)i * 9;
        const float* p2 = cov2 + (size_t)i * 9;
        #pragma unroll
        for (int k = 0; k < 9; ++k) { c1[k] = p1[k]; c2r[k] = p2[k]; }
        const float* q1p = miu1 + (size_t)i * 3;
        const float* q2p = miu2 + (size_t)i * 3;
        #pragma unroll
        for (int k = 0; k < 3; ++k) { u1[k] = q1p[k]; u2[k] = q2p[k]; }
    }

    // ---- stability mask (abs folds into VOP3 input modifiers; keep scalar) ----
    float amax1 = 0.0f, amax2 = 0.0f, amin1 = 1e30f, amin2 = 1e30f;
    #pragma unroll
    for (int k = 0; k < 9; ++k) {
        amax1 = fmaxf(amax1, fabsf(c1[k]));  amin1 = fminf(amin1, fabsf(c1[k]));
        amax2 = fmaxf(amax2, fabsf(c2r[k])); amin2 = fminf(amin2, fabsf(c2r[k]));
    }
    bool ok = (amax1 < MAX_COV) && (amax2 < MAX_COV)
           && (amin1 > MIN_COV) && (amin2 > MIN_COV);
    const float sd = fmaxf(fmaxf(fabsf(c1[1] - c1[3]), fabsf(c1[2] - c1[6])),
                    fmaxf(fabsf(c1[5] - c1[7]),
                    fmaxf(fmaxf(fabsf(c2r[1] - c2r[3]), fabsf(c2r[2] - c2r[6])),
                          fabsf(c2r[5] - c2r[7]))));
    ok = ok && (sd < SYMM_THRESH);
    const float det1 = c1[0] * (c1[4] * c1[8] - c1[5] * c1[7])
                     - c1[1] * (c1[3] * c1[8] - c1[5] * c1[6])
                     + c1[2] * (c1[3] * c1[7] - c1[4] * c1[6]);
    const float det2 = c2r[0] * (c2r[4] * c2r[8] - c2r[5] * c2r[7])
                     - c2r[1] * (c2r[3] * c2r[8] - c2r[5] * c2r[6])
                     + c2r[2] * (c2r[3] * c2r[7] - c2r[4] * c2r[6]);
    ok = ok && (fabsf(det1) > DET_THRESH) && (fabsf(det2) > DET_THRESH);
    const float um = fmaxf(fmaxf(fmaxf(fabsf(u1[0]), fabsf(u1[1])), fabsf(u1[2])),
                           fmaxf(fmaxf(fabsf(u2[0]), fabsf(u2[1])), fabsf(u2[2])));
    ok = ok && (um < MAX_POS);

    // ---- symmetrized inputs (packed adds); masked items -> identity ----
    const v2f md01 = 0.5f * (mk2(c1[1], c2r[1]) + mk2(c1[3], c2r[3]));
    const v2f md02 = 0.5f * (mk2(c1[2], c2r[2]) + mk2(c1[6], c2r[6]));
    const v2f md12 = 0.5f * (mk2(c1[5], c2r[5]) + mk2(c1[7], c2r[7]));
    const float m00 = ok ? c1[0] : 1.0f;
    const float m11 = ok ? c1[4] : 1.0f;
    const float m22 = ok ? c1[8] : 1.0f;
    const float m01 = ok ? md01[0] : 0.0f;
    const float m02 = ok ? md02[0] : 0.0f;
    const float m12 = ok ? md12[0] : 0.0f;
    const float d00 = ok ? c2r[0] : 1.0f;
    const float d11 = ok ? c2r[4] : 1.0f;
    const float d22 = ok ? c2r[8] : 1.0f;
    const float d01 = ok ? md01[1] : 0.0f;
    const float d02 = ok ? md02[1] : 0.0f;
    const float d12 = ok ? md12[1] : 0.0f;

    float l1, l2, l3;
    eigvals3(m00, m01, m02, m11, m12, m22, l1, l2, l3);
    l1 = fmaxf(l1, EIG_CLAMP); l2 = fmaxf(l2, EIG_CLAMP); l3 = fmaxf(l3, EIG_CLAMP);
    const float sa = sqrt_fast(l1), sb = sqrt_fast(l2), sc = sqrt_fast(l3);
    const float i_ab = rcp_fast(sa + sb);
    const float i_bc = rcp_fast(sb + sc);
    const float i_ac = rcp_fast(sa + sc);
    const float ea = rcp_fast(INV_EPS + sa);
    const float eb = rcp_fast(INV_EPS + sb);
    const float ec = rcp_fast(INV_EPS + sc);
    // Newton coefficients for f=sqrt (q*) and f=1/(eps+sqrt) (g*), packed.
    const v2f qg0 = mk2(sa, ea);
    const v2f qg1 = mk2(i_ab, -ea * eb * i_ab);
    const v2f qg2 = mk2(-i_ab * i_bc * i_ac,
                        (INV_EPS + sa + sb + sc) * ea * eb * ec * i_ab * i_bc * i_ac);

    // U = M - l1*I, V = M - l2*I, P = U*V (symmetric); packed pairs
    const float u00 = m00 - l1, u11 = m11 - l1, u22 = m22 - l1;
    const float v00 = m00 - l2, v11 = m11 - l2, v22 = m22 - l2;
    const v2f PA = u00 * mk2(v00, m01) + m01 * mk2(m01, v11) + m02 * mk2(m02, m12); // P00,P01
    const v2f PB = mk2(u00, m01) * mk2(m02, m01) + mk2(m01, u11) * mk2(m12, v11)
                 + mk2(m02, m12) * mk2(v22, m12);                                    // P02,P11
    const v2f PC = mk2(m01, m02) * mk2(m02, m02) + mk2(u11, m12) * mk2(m12, m12)
                 + mk2(m12, u22) * mk2(v22, v22);                                    // P12,P22

    // A_sqrt (S) and A_sqrt_inv (G) share the Newton basis: pack (S_ij, G_ij)
    const v2f SG00 = qg0 + qg1 * u00 + qg2 * PA[0];
    const v2f SG01 =       qg1 * m01 + qg2 * PA[1];
    const v2f SG02 =       qg1 * m02 + qg2 * PB[0];
    const v2f SG11 = qg0 + qg1 * u11 + qg2 * PB[1];
    const v2f SG12 =       qg1 * m12 + qg2 * PC[0];
    const v2f SG22 = qg0 + qg1 * u22 + qg2 * PC[1];
    const float S00 = SG00[0], G00 = SG00[1];
    const float S01 = SG01[0], G01 = SG01[1];
    const float S02 = SG02[0], G02 = SG02[1];
    const float S11 = SG11[0], G11 = SG11[1];
    const float S12 = SG12[0], G12 = SG12[1];
    const float S22 = SG22[0], G22 = SG22[1];

    // T = S*D (full), C = T*S (6 unique) — packed
    const v2f TA = S00 * mk2(d00, d01) + S01 * mk2(d01, d11) + S02 * mk2(d02, d12); // T00,T01
    const v2f TB = mk2(S00, S01) * mk2(d02, d00) + mk2(S01, S11) * mk2(d12, d01)
                 + mk2(S02, S12) * mk2(d22, d02);                                    // T02,T10
    const v2f TC = S01 * mk2(d01, d02) + S11 * mk2(d11, d12) + S12 * mk2(d12, d22); // T11,T12
    const v2f TD = S02 * mk2(d00, d01) + S12 * mk2(d01, d11) + S22 * mk2(d02, d12); // T20,T21
    const float T00 = TA[0], T01 = TA[1], T02 = TB[0], T10 = TB[1];
    const float T11 = TC[0], T12 = TC[1], T20 = TD[0], T21 = TD[1];
    const float T22 = S02 * d02 + S12 * d12 + S22 * d22;

    const v2f CA = T00 * mk2(S00, S01) + T01 * mk2(S01, S11) + T02 * mk2(S02, S12); // C00,C01
    const v2f CB = mk2(T00, T10) * mk2(S02, S01) + mk2(T01, T11) * mk2(S12, S11)
                 + mk2(T02, T12) * mk2(S22, S12);                                    // C02,C11
    const v2f CC = mk2(T10, T20) * S02 + mk2(T11, T21) * S12 + mk2(T12, T22) * S22; // C12,C22
    const float C00 = CA[0], C01 = CA[1], C02 = CB[0];
    const float C11 = CB[1], C12 = CC[0], C22 = CC[1];

    // C_sqrt: f(lambda) = sqrt(|lambda|)
    float e1, e2, e3;
    eigvals3(C00, C01, C02, C11, C12, C22, e1, e2, e3);
    const float ra = sqrt_fast(fabsf(e1));
    const float rb = sqrt_fast(fabsf(e2));
    const float rc = sqrt_fast(fabsf(e3));
    const float j_ab = rcp_fast(fmaxf(ra + rb, 1e-12f));
    const float j_bc = rcp_fast(fmaxf(rb + rc, 1e-12f));
    const float j_ac = rcp_fast(fmaxf(ra + rc, 1e-12f));
    const float h0 = ra, h1 = j_ab, h2 = -j_ab * j_bc * j_ac;
    const float cu00 = C00 - e1, cu11 = C11 - e1, cu22 = C22 - e1;
    const float cv00 = C00 - e2, cv11 = C11 - e2, cv22 = C22 - e2;
    const v2f RA = cu00 * mk2(cv00, C01) + C01 * mk2(C01, cv11) + C02 * mk2(C02, C12); // R00,R01
    const v2f RB = mk2(cu00, C01) * mk2(C02, C01) + mk2(C01, cu11) * mk2(C12, cv11)
                 + mk2(C02, C12) * mk2(cv22, C12);                                      // R02,R11
    const v2f RC = mk2(C01, C02) * mk2(C02, C02) + mk2(cu11, C12) * mk2(C12, C12)
                 + mk2(C12, cu22) * mk2(cv22, cv22);                                    // R12,R22

    const v2f XA = mk2(h0, 0.0f) + h1 * mk2(cu00, C01) + h2 * mk2(RA[0], RA[1]); // X00,X01
    const v2f XB = mk2(h0, 0.0f) + h1 * mk2(cu11, C02) + h2 * mk2(RB[1], RB[0]); // X11,X02
    const v2f XC = mk2(h0, 0.0f) + h1 * mk2(cu22, C12) + h2 * mk2(RC[1], RC[0]); // X22,X12
    const float X00 = XA[0], X01 = XA[1], X11 = XB[0], X02 = XB[1];
    const float X22 = XC[0], X12 = XC[1];

    // A = S * X, W = A * G — packed
    const v2f AA = S00 * mk2(X00, X01) + S01 * mk2(X01, X11) + S02 * mk2(X02, X12); // A00,A01
    const v2f AB = mk2(S00, S01) * mk2(X02, X00) + mk2(S01, S11) * mk2(X12, X01)
                 + mk2(S02, S12) * mk2(X22, X02);                                    // A02,A10
    const v2f AC = S01 * mk2(X01, X02) + S11 * mk2(X11, X12) + S12 * mk2(X12, X22); // A11,A12
    const v2f AD = S02 * mk2(X00, X01) + S12 * mk2(X01, X11) + S22 * mk2(X02, X12); // A20,A21
    const float A00 = AA[0], A01 = AA[1], A02 = AB[0], A10 = AB[1];
    const float A11 = AC[0], A12 = AC[1], A20 = AD[0], A21 = AD[1];
    const float A22 = S02 * X02 + S12 * X12 + S22 * X22;

    const v2f WA = A00 * mk2(G00, G01) + A01 * mk2(G01, G11) + A02 * mk2(G02, G12); // W0,W1
    const v2f WB = mk2(A00, A10) * mk2(G02, G00) + mk2(A01, A11) * mk2(G12, G01)
                 + mk2(A02, A12) * mk2(G22, G02);                                    // W2,W3
    const v2f WC = A10 * mk2(G01, G02) + A11 * mk2(G11, G12) + A12 * mk2(G12, G22); // W4,W5
    const v2f WD = A20 * mk2(G00, G01) + A21 * mk2(G01, G11) + A22 * mk2(G02, G12); // W6,W7
    const float W0 = WA[0], W1 = WA[1], W2 = WB[0], W3 = WB[1];
    const float W4 = WC[0], W5 = WC[1], W6 = WD[0], W7 = WD[1];
    const float W8 = A20 * G02 + A21 * G12 + A22 * G22;

    // cov_vel = W + W^T - 2*sym(cov_1): 6 unique entries, packed
    const v2f EA = mk2(W0, W1) + mk2(W0, W3) - 2.0f * mk2(m00, m01); // E00,E01
    const v2f EB = mk2(W2, W4) + mk2(W6, W4) - 2.0f * mk2(m02, m11); // E02,E11
    const v2f EC = mk2(W5, W8) + mk2(W7, W8) - 2.0f * mk2(m12, m22); // E12,E22

    float* out_cov = out + (size_t)N * 3;
    float* oc = out_cov + (size_t)i * 9;
    oc[0] = ok ? EA[0] : 0.0f;
    oc[1] = ok ? EA[1] : 0.0f;
    oc[2] = ok ? EB[0] : 0.0f;
    oc[3] = ok ? EA[1] : 0.0f;
    oc[4] = ok ? EB[1] : 0.0f;
    oc[5] = ok ? EC[0] : 0.0f;
    oc[6] = ok ? EB[0] : 0.0f;
    oc[7] = ok ? EC[0] : 0.0f;
    oc[8] = ok ? EC[1] : 0.0f;
    float* om = out + (size_t)i * 3;
    #pragma unroll
    for (int k = 0; k < 3; ++k) om[k] = ok ? (u2[k] - u1[k]) : 0.0f;
}

} // namespace

extern "C" void kernel_launch(void* const* d_in, const int* in_sizes, int n_in,
                              void* d_out, int out_size, void* d_ws, size_t ws_size,
                              hipStream_t stream)
{
    const float* miu1 = (const float*)d_in[0];
    const float* miu2 = (const float*)d_in[1];
    const float* cov1 = (const float*)d_in[2];
    const float* cov2 = (const float*)d_in[3];
    float* out = (float*)d_out;
    const int N = in_sizes[0] / 3;
    const int grid = (N + BS - 1) / BS;
    hipLaunchKernelGGL(wl_kernel, dim3(grid), dim3(BS), 0, stream,
                       miu1, miu2, cov1, cov2, out, N);
}